// Round 5
// baseline (545.251 us; speedup 1.0000x reference)
//
#include <hip/hip_runtime.h>
#include <hip/hip_bf16.h>

#define N_ROWS 8192
#define DIM    128
#define TWO_N  16384
#define NBLK   64                         // 256-row/col block stripes
#define NTRI   (NBLK * (NBLK + 1) / 2)    // 2080 triangular blocks
#define CT     32                         // cols per LDS tile
#define NT     8                          // 256 cols per block / CT
#define EXP_TWO 7.38905609893065f
// sqrt(2 * log2(e)): folding exp(2*dot) == exp2(SCALE^2 * dot) into the operands
#define H_SCALE 1.6986436f

typedef __attribute__((ext_vector_type(8))) short short8;
typedef __attribute__((ext_vector_type(4))) float float4v;

__device__ inline void async_copy16(const void* g, void* l) {
  __builtin_amdgcn_global_load_lds(
      (const __attribute__((address_space(1))) void*)g,
      (__attribute__((address_space(3))) void*)l, 16, 0, 0);
}

__device__ inline float fast_exp2(float x) {
#if __has_builtin(__builtin_amdgcn_exp2f)
  return __builtin_amdgcn_exp2f(x);
#else
  return exp2f(x);
#endif
}

// ---------------------------------------------------------------------------
// Kernel 1: L2-normalize rows of h1,h2 (fp32), write bf16 H = [h1n; h2n]
// scaled by sqrt(2*log2 e) so the GEMM accumulator is already the exp2 arg.
// Writes exact fp32 pos-dot per row, zeroes rowsum and the completion
// counter used by ntx_main's fused finalize.
// ---------------------------------------------------------------------------
__global__ __launch_bounds__(256) void norm_kernel(
    const float* __restrict__ h1, const float* __restrict__ h2,
    __hip_bfloat16* __restrict__ Hb, float* __restrict__ posdot,
    float* __restrict__ rowsum, int* __restrict__ counter) {
  // zero rowsum[16384]: 2048 blocks x 8 entries; block 0 zeroes the counter
  if (threadIdx.x < 8) rowsum[blockIdx.x * 8 + threadIdx.x] = 0.0f;
  if (blockIdx.x == 0 && threadIdx.x == 0) *counter = 0;

  int lane = threadIdx.x & 63;
  int w    = threadIdx.x >> 6;
  int row  = blockIdx.x * 4 + w;                  // 0..8191

  const float2* p1 = (const float2*)(h1 + (size_t)row * DIM);
  const float2* p2 = (const float2*)(h2 + (size_t)row * DIM);
  float2 v1 = p1[lane];
  float2 v2 = p2[lane];

  float ss1 = v1.x * v1.x + v1.y * v1.y;
  float ss2 = v2.x * v2.x + v2.y * v2.y;
  #pragma unroll
  for (int m = 32; m; m >>= 1) {
    ss1 += __shfl_xor(ss1, m);
    ss2 += __shfl_xor(ss2, m);
  }
  float inv1 = 1.0f / fmaxf(sqrtf(ss1), 1e-12f);
  float inv2 = 1.0f / fmaxf(sqrtf(ss2), 1e-12f);

  float ax = v1.x * inv1, ay = v1.y * inv1;
  float bx = v2.x * inv2, by = v2.y * inv2;

  float pd = ax * bx + ay * by;       // exact fp32 posdot (unscaled)
  #pragma unroll
  for (int m = 32; m; m >>= 1) pd += __shfl_xor(pd, m);

  __hip_bfloat162* o1 = (__hip_bfloat162*)(Hb + (size_t)row * DIM);
  __hip_bfloat162* o2 = (__hip_bfloat162*)(Hb + (size_t)(row + N_ROWS) * DIM);
  __hip_bfloat162 t1, t2;
  t1.x = __float2bfloat16(ax * H_SCALE); t1.y = __float2bfloat16(ay * H_SCALE);
  t2.x = __float2bfloat16(bx * H_SCALE); t2.y = __float2bfloat16(by * H_SCALE);
  o1[lane] = t1;
  o2[lane] = t2;

  if (lane == 0) posdot[row] = pd;
}

// ---------------------------------------------------------------------------
// Kernel 2: row sums of exp2(H H^T), upper block-triangle only (symmetry).
// 512 threads = 8 waves; each wave owns 32 rows (A pinned: 32 VGPRs).
// B tiles (32 cols x 128 k) in a 3-deep LDS pipeline staged via
// global_load_lds in MFMA fragment order. Counted-vmcnt schedule (T3/T4):
//   per tile: s_waitcnt vmcnt(1); s_barrier; issue stage t+2; compute t
// -> the two newest stages stay in flight across barriers, never drained
// to 0 in the loop. Stage-after-barrier removes the WAR race on the
// recycled buffer (all waves passed compute t-1 before its buffer is
// overwritten by stage t+2).
// Off-diagonal blocks also accumulate column sums (symmetric half) into
// per-wave LDS slices, flushed once at the end.
// The LAST block to finish (device-scope counter) runs the finalize
// reduction inline, reading rowsum via atomic-adds of 0 (XCD-safe).
// ---------------------------------------------------------------------------
__global__ __launch_bounds__(512, 4) void ntx_main(
    const __hip_bfloat16* __restrict__ Hb, float* __restrict__ rowsum,
    const float* __restrict__ posdot, int* __restrict__ counter,
    float* __restrict__ out) {
  __shared__ short smem[3 * 4096];    // 24 KB: 3 B-tile buffers
  __shared__ float colacc[8][256];    // 8 KB: per-wave col-sum slices
  __shared__ float red[16];
  __shared__ int is_last;
  const short* H = (const short*)Hb;

  int tid  = threadIdx.x;
  int lane = tid & 63;
  int w    = tid >> 6;      // 0..7
  int q    = lane >> 4;     // k-chunk selector within fragment
  int m    = lane & 15;     // row-within-subtile / col-within-subtile

  // Triangular decode: blockIdx.x -> (I, J) with J >= I over NBLK stripes.
  int t0 = blockIdx.x;
  int I = (int)((129.0f - sqrtf(129.0f * 129.0f - 8.0f * (float)t0)) * 0.5f);
  while ((I + 1) * (129 - (I + 1)) / 2 <= t0) ++I;   // fixup fp rounding
  while (I * (129 - I) / 2 > t0) --I;
  int J = I + (t0 - I * (129 - I) / 2);
  bool diag = (I == J);

  int rowbase = I * 256 + w * 32;
  int colbase = J * 256;

  // A fragments: 2 row-subtiles x 4 k-steps (32 rows per wave), pinned.
  short8 a[2][4];
  #pragma unroll
  for (int r = 0; r < 2; ++r)
    #pragma unroll
    for (int s = 0; s < 4; ++s)
      a[r][s] = *(const short8*)(H + (size_t)(rowbase + r * 16 + m) * DIM + s * 32 + q * 8);
  #pragma unroll
  for (int r = 0; r < 2; ++r)
    #pragma unroll
    for (int s = 0; s < 4; ++s)
      asm volatile("" : "+v"(a[r][s]));

  float rowacc[2][4];
  #pragma unroll
  for (int r = 0; r < 2; ++r)
    #pragma unroll
    for (int i = 0; i < 4; ++i) rowacc[r][i] = 0.0f;

  // Staging: one 16B chunk per thread per tile, MFMA fragment order.
  // chunk i=tid -> c=i>>8, s=(i>>6)&3, l15=i&15, lq=(i>>4)&3; LDS dest i*16B.
  int c0 = tid >> 8, s0 = (tid >> 6) & 3, f0 = tid & 15, q0 = (tid >> 4) & 3;
  const short* ga = H + (size_t)(colbase + c0 * 16 + f0) * DIM + s0 * 32 + q0 * 8;

  // Prologue: stage tiles 0 and 1.
  async_copy16(ga, (void*)&smem[tid * 8]);
  async_copy16(ga + CT * DIM, (void*)&smem[4096 + tid * 8]);
  const short* gs = ga + 2 * CT * DIM;

  #pragma unroll
  for (int t = 0; t < NT; ++t) {
    // Drain only up to the oldest outstanding stage (counted, never 0
    // until the last tile). Safe even if other vmem interleaves: vmcnt(1)
    // leaves at most the single newest op in flight -> stage t is drained.
    if (t < NT - 1) asm volatile("s_waitcnt vmcnt(1)" ::: "memory");
    else            asm volatile("s_waitcnt vmcnt(0)" ::: "memory");
    __builtin_amdgcn_sched_barrier(0);
    __builtin_amdgcn_s_barrier();
    __builtin_amdgcn_sched_barrier(0);

    // Stage tile t+2 into the buffer freed by compute t-1 (all waves are
    // past it: they crossed this barrier after finishing compute t-1).
    if (t + 2 < NT) {
      async_copy16(gs, (void*)&smem[((t + 2) % 3) * 4096 + tid * 8]);
      gs += CT * DIM;
    }

    const short* bsrc = &smem[(t % 3) * 4096];
    #pragma unroll
    for (int c = 0; c < 2; ++c) {
      short8 b[4];
      #pragma unroll
      for (int s = 0; s < 4; ++s)
        b[s] = *(const short8*)&bsrc[(c * 256 + s * 64 + lane) * 8];
      float cp = 0.0f;
      #pragma unroll
      for (int r = 0; r < 2; ++r) {
        float4v acc = {0.f, 0.f, 0.f, 0.f};
        #pragma unroll
        for (int s = 0; s < 4; ++s)
          acc = __builtin_amdgcn_mfma_f32_16x16x32_bf16(a[r][s], b[s], acc, 0, 0, 0);
        #pragma unroll
        for (int i = 0; i < 4; ++i) {
          float e = fast_exp2(acc[i]);   // acc already = 2*log2e*dot
          rowacc[r][i] += e;
          cp += e;
        }
      }
      if (!diag) {
        // sum over the 4 q-groups -> col sum over this wave's 32 rows
        cp += __shfl_xor(cp, 16);
        cp += __shfl_xor(cp, 32);
        if (q == 0) colacc[w][t * CT + c * 16 + m] = cp;
      }
    }
  }

  // Row sums: reduce across the 16 column-lanes holding the same rows.
  #pragma unroll
  for (int r = 0; r < 2; ++r)
    #pragma unroll
    for (int i = 0; i < 4; ++i) {
      float v = rowacc[r][i];
      v += __shfl_xor(v, 1);
      v += __shfl_xor(v, 2);
      v += __shfl_xor(v, 4);
      v += __shfl_xor(v, 8);
      rowacc[r][i] = v;
    }
  if (m == 0) {
    #pragma unroll
    for (int r = 0; r < 2; ++r)
      #pragma unroll
      for (int i = 0; i < 4; ++i)
        atomicAdd(&rowsum[rowbase + r * 16 + q * 4 + i], rowacc[r][i]);
  }

  // Col sums -> stripe J (symmetric contribution).
  if (!diag) {
    __syncthreads();
    if (tid < 256) {
      float v = 0.0f;
      #pragma unroll
      for (int ww = 0; ww < 8; ++ww) v += colacc[ww][tid];
      atomicAdd(&rowsum[colbase + tid], v);
    }
  }

  // ---- fused finalize: last block computes the loss ----
  __threadfence();          // order this thread's rowsum atomics
  __syncthreads();          // all waves drained (vmcnt) + fenced
  if (tid == 0) {
    int old = atomicAdd(counter, 1);
    is_last = (old == NTRI - 1) ? 1 : 0;
  }
  __syncthreads();
  if (is_last) {
    float ld = 0.0f, pp = 0.0f;
    for (int i = tid; i < TWO_N; i += 512) {
      float v = atomicAdd(&rowsum[i], 0.0f);   // device-scope read, XCD-safe
      ld += logf(v - EXP_TWO);
    }
    for (int i = tid; i < N_ROWS; i += 512) pp += posdot[i];
    #pragma unroll
    for (int s = 32; s; s >>= 1) {
      ld += __shfl_xor(ld, s);
      pp += __shfl_xor(pp, s);
    }
    if (lane == 0) { red[w] = ld; red[8 + w] = pp; }
    __syncthreads();
    if (tid == 0) {
      float tl = 0.0f, tp = 0.0f;
      #pragma unroll
      for (int i = 0; i < 8; ++i) { tl += red[i]; tp += red[8 + i]; }
      *out = (tl - 4.0f * tp) / (float)TWO_N;
    }
  }
}

extern "C" void kernel_launch(void* const* d_in, const int* in_sizes, int n_in,
                              void* d_out, int out_size, void* d_ws, size_t ws_size,
                              hipStream_t stream) {
  const float* h1 = (const float*)d_in[0];
  const float* h2 = (const float*)d_in[1];
  char* ws = (char*)d_ws;

  __hip_bfloat16* Hb = (__hip_bfloat16*)ws;                       // 4 MB
  float* rowsum      = (float*)(ws + 4194304);                    // 64 KB
  float* posdot      = (float*)(ws + 4194304 + 65536);            // 32 KB
  int*   counter     = (int*)(ws + 4194304 + 65536 + 32768);      // 4 B
  float* out         = (float*)d_out;

  norm_kernel<<<N_ROWS / 4, 256, 0, stream>>>(h1, h2, Hb, posdot, rowsum, counter);
  ntx_main<<<NTRI, 512, 0, stream>>>(Hb, rowsum, posdot, counter, out);
}

// Round 6
// 374.758 us; speedup vs baseline: 1.4549x; 1.4549x over previous
//
#include <hip/hip_runtime.h>
#include <hip/hip_bf16.h>

#define N_ROWS 8192
#define DIM    128
#define TWO_N  16384
#define NBLK   64                         // 256-row/col block stripes
#define NTRI   (NBLK * (NBLK + 1) / 2)    // 2080 triangular blocks
#define CT     32                         // cols per LDS tile
#define NT     8                          // 256 cols per block / CT
#define EXP_TWO 7.38905609893065f
// sqrt(2 * log2(e)): folding exp(2*dot) == exp2(SCALE^2 * dot) into the operands
#define H_SCALE 1.6986436f

typedef __attribute__((ext_vector_type(8))) short short8;
typedef __attribute__((ext_vector_type(4))) float float4v;

__device__ inline void async_copy16(const void* g, void* l) {
  __builtin_amdgcn_global_load_lds(
      (const __attribute__((address_space(1))) void*)g,
      (__attribute__((address_space(3))) void*)l, 16, 0, 0);
}

__device__ inline float fast_exp2(float x) {
#if __has_builtin(__builtin_amdgcn_exp2f)
  return __builtin_amdgcn_exp2f(x);
#else
  return exp2f(x);
#endif
}

// ---------------------------------------------------------------------------
// Kernel 1: L2-normalize rows of h1,h2 (fp32), write bf16 H = [h1n; h2n]
// scaled by sqrt(2*log2 e) so the GEMM accumulator is already the exp2 arg.
// Writes exact fp32 pos-dot per row, zeroes rowsum and the completion
// counter used by ntx_main's fused finalize.
// ---------------------------------------------------------------------------
__global__ __launch_bounds__(256) void norm_kernel(
    const float* __restrict__ h1, const float* __restrict__ h2,
    __hip_bfloat16* __restrict__ Hb, float* __restrict__ posdot,
    float* __restrict__ rowsum, int* __restrict__ counter) {
  // zero rowsum[16384]: 2048 blocks x 8 entries; block 0 zeroes the counter
  if (threadIdx.x < 8) rowsum[blockIdx.x * 8 + threadIdx.x] = 0.0f;
  if (blockIdx.x == 0 && threadIdx.x == 0) *counter = 0;

  int lane = threadIdx.x & 63;
  int w    = threadIdx.x >> 6;
  int row  = blockIdx.x * 4 + w;                  // 0..8191

  const float2* p1 = (const float2*)(h1 + (size_t)row * DIM);
  const float2* p2 = (const float2*)(h2 + (size_t)row * DIM);
  float2 v1 = p1[lane];
  float2 v2 = p2[lane];

  float ss1 = v1.x * v1.x + v1.y * v1.y;
  float ss2 = v2.x * v2.x + v2.y * v2.y;
  #pragma unroll
  for (int m = 32; m; m >>= 1) {
    ss1 += __shfl_xor(ss1, m);
    ss2 += __shfl_xor(ss2, m);
  }
  float inv1 = 1.0f / fmaxf(sqrtf(ss1), 1e-12f);
  float inv2 = 1.0f / fmaxf(sqrtf(ss2), 1e-12f);

  float ax = v1.x * inv1, ay = v1.y * inv1;
  float bx = v2.x * inv2, by = v2.y * inv2;

  float pd = ax * bx + ay * by;       // exact fp32 posdot (unscaled)
  #pragma unroll
  for (int m = 32; m; m >>= 1) pd += __shfl_xor(pd, m);

  __hip_bfloat162* o1 = (__hip_bfloat162*)(Hb + (size_t)row * DIM);
  __hip_bfloat162* o2 = (__hip_bfloat162*)(Hb + (size_t)(row + N_ROWS) * DIM);
  __hip_bfloat162 t1, t2;
  t1.x = __float2bfloat16(ax * H_SCALE); t1.y = __float2bfloat16(ay * H_SCALE);
  t2.x = __float2bfloat16(bx * H_SCALE); t2.y = __float2bfloat16(by * H_SCALE);
  o1[lane] = t1;
  o2[lane] = t2;

  if (lane == 0) posdot[row] = pd;
}

// ---------------------------------------------------------------------------
// Kernel 2: row sums of exp2(H H^T), upper block-triangle only (symmetry).
// 512 threads = 8 waves; each wave owns 32 rows (A pinned: 32 VGPRs).
// B tiles (32 cols x 128 k) in a 3-deep LDS pipeline staged via
// global_load_lds in MFMA fragment order. Counted-vmcnt schedule (T3/T4):
//   per tile: s_waitcnt vmcnt(1); s_barrier; issue stage t+2; compute t
// -> the two newest stages stay in flight across barriers, never drained
// to 0 in the loop. wait-then-barrier => every wave's stage of tile t is
// complete when any wave crosses the barrier (collective completion).
// NOTE: __launch_bounds__ 2nd arg: 4 produced a 64-VGPR cap (8 waves/EU)
// and catastrophic scratch spills (R5: 330 MB scratch traffic). 2 -> 128
// VGPR cap, ~2 blocks/CU, no spills.
// Off-diagonal blocks also accumulate column sums (symmetric half) into
// per-wave LDS slices, flushed once at the end.
// The LAST block to finish (device-scope counter) runs the finalize
// reduction inline, reading rowsum via atomic-adds of 0 (XCD-safe).
// ---------------------------------------------------------------------------
__global__ __launch_bounds__(512, 2) void ntx_main(
    const __hip_bfloat16* __restrict__ Hb, float* __restrict__ rowsum,
    const float* __restrict__ posdot, int* __restrict__ counter,
    float* __restrict__ out) {
  __shared__ short smem[3 * 4096];    // 24 KB: 3 B-tile buffers
  __shared__ float colacc[8][256];    // 8 KB: per-wave col-sum slices
  __shared__ float red[16];
  __shared__ int is_last;
  const short* H = (const short*)Hb;

  int tid  = threadIdx.x;
  int lane = tid & 63;
  int w    = tid >> 6;      // 0..7
  int q    = lane >> 4;     // k-chunk selector within fragment
  int m    = lane & 15;     // row-within-subtile / col-within-subtile

  // Triangular decode: blockIdx.x -> (I, J) with J >= I over NBLK stripes.
  int t0 = blockIdx.x;
  int I = (int)((129.0f - sqrtf(129.0f * 129.0f - 8.0f * (float)t0)) * 0.5f);
  while ((I + 1) * (129 - (I + 1)) / 2 <= t0) ++I;   // fixup fp rounding
  while (I * (129 - I) / 2 > t0) --I;
  int J = I + (t0 - I * (129 - I) / 2);
  bool diag = (I == J);

  int rowbase = I * 256 + w * 32;
  int colbase = J * 256;

  // A fragments: 2 row-subtiles x 4 k-steps (32 rows per wave), pinned.
  short8 a[2][4];
  #pragma unroll
  for (int r = 0; r < 2; ++r)
    #pragma unroll
    for (int s = 0; s < 4; ++s)
      a[r][s] = *(const short8*)(H + (size_t)(rowbase + r * 16 + m) * DIM + s * 32 + q * 8);
  #pragma unroll
  for (int r = 0; r < 2; ++r)
    #pragma unroll
    for (int s = 0; s < 4; ++s)
      asm volatile("" : "+v"(a[r][s]));

  float rowacc[2][4];
  #pragma unroll
  for (int r = 0; r < 2; ++r)
    #pragma unroll
    for (int i = 0; i < 4; ++i) rowacc[r][i] = 0.0f;

  // Staging: one 16B chunk per thread per tile, MFMA fragment order.
  // chunk i=tid -> c=i>>8, s=(i>>6)&3, l15=i&15, lq=(i>>4)&3; LDS dest i*16B.
  int c0 = tid >> 8, s0 = (tid >> 6) & 3, f0 = tid & 15, q0 = (tid >> 4) & 3;
  const short* ga = H + (size_t)(colbase + c0 * 16 + f0) * DIM + s0 * 32 + q0 * 8;

  // Prologue: stage tiles 0 and 1.
  async_copy16(ga, (void*)&smem[tid * 8]);
  async_copy16(ga + CT * DIM, (void*)&smem[4096 + tid * 8]);
  const short* gs = ga + 2 * CT * DIM;

  #pragma unroll
  for (int t = 0; t < NT; ++t) {
    // Drain only up to the oldest outstanding stage (counted, never 0
    // until the last tile).
    if (t < NT - 1) asm volatile("s_waitcnt vmcnt(1)" ::: "memory");
    else            asm volatile("s_waitcnt vmcnt(0)" ::: "memory");
    __builtin_amdgcn_sched_barrier(0);
    __builtin_amdgcn_s_barrier();
    __builtin_amdgcn_sched_barrier(0);

    // Stage tile t+2 into the buffer freed by compute t-1 (all waves are
    // past it: they crossed this barrier after finishing compute t-1).
    if (t + 2 < NT) {
      async_copy16(gs, (void*)&smem[((t + 2) % 3) * 4096 + tid * 8]);
      gs += CT * DIM;
    }

    const short* bsrc = &smem[(t % 3) * 4096];
    #pragma unroll
    for (int c = 0; c < 2; ++c) {
      short8 b[4];
      #pragma unroll
      for (int s = 0; s < 4; ++s)
        b[s] = *(const short8*)&bsrc[(c * 256 + s * 64 + lane) * 8];
      float cp = 0.0f;
      #pragma unroll
      for (int r = 0; r < 2; ++r) {
        float4v acc = {0.f, 0.f, 0.f, 0.f};
        #pragma unroll
        for (int s = 0; s < 4; ++s)
          acc = __builtin_amdgcn_mfma_f32_16x16x32_bf16(a[r][s], b[s], acc, 0, 0, 0);
        #pragma unroll
        for (int i = 0; i < 4; ++i) {
          float e = fast_exp2(acc[i]);   // acc already = 2*log2e*dot
          rowacc[r][i] += e;
          cp += e;
        }
      }
      if (!diag) {
        // sum over the 4 q-groups -> col sum over this wave's 32 rows
        cp += __shfl_xor(cp, 16);
        cp += __shfl_xor(cp, 32);
        if (q == 0) colacc[w][t * CT + c * 16 + m] = cp;
      }
    }
  }

  // Row sums: reduce across the 16 column-lanes holding the same rows.
  #pragma unroll
  for (int r = 0; r < 2; ++r)
    #pragma unroll
    for (int i = 0; i < 4; ++i) {
      float v = rowacc[r][i];
      v += __shfl_xor(v, 1);
      v += __shfl_xor(v, 2);
      v += __shfl_xor(v, 4);
      v += __shfl_xor(v, 8);
      rowacc[r][i] = v;
    }
  if (m == 0) {
    #pragma unroll
    for (int r = 0; r < 2; ++r)
      #pragma unroll
      for (int i = 0; i < 4; ++i)
        atomicAdd(&rowsum[rowbase + r * 16 + q * 4 + i], rowacc[r][i]);
  }

  // Col sums -> stripe J (symmetric contribution).
  if (!diag) {
    __syncthreads();
    if (tid < 256) {
      float v = 0.0f;
      #pragma unroll
      for (int ww = 0; ww < 8; ++ww) v += colacc[ww][tid];
      atomicAdd(&rowsum[colbase + tid], v);
    }
  }

  // ---- fused finalize: last block computes the loss ----
  __threadfence();          // order this thread's rowsum atomics
  __syncthreads();
  if (tid == 0) {
    int old = atomicAdd(counter, 1);
    is_last = (old == NTRI - 1) ? 1 : 0;
  }
  __syncthreads();
  if (is_last) {
    float ld = 0.0f, pp = 0.0f;
    for (int i = tid; i < TWO_N; i += 512) {
      float v = atomicAdd(&rowsum[i], 0.0f);   // device-scope read, XCD-safe
      ld += logf(v - EXP_TWO);
    }
    for (int i = tid; i < N_ROWS; i += 512) pp += posdot[i];
    #pragma unroll
    for (int s = 32; s; s >>= 1) {
      ld += __shfl_xor(ld, s);
      pp += __shfl_xor(pp, s);
    }
    if (lane == 0) { red[w] = ld; red[8 + w] = pp; }
    __syncthreads();
    if (tid == 0) {
      float tl = 0.0f, tp = 0.0f;
      #pragma unroll
      for (int i = 0; i < 8; ++i) { tl += red[i]; tp += red[8 + i]; }
      *out = (tl - 4.0f * tp) / (float)TWO_N;
    }
  }
}

extern "C" void kernel_launch(void* const* d_in, const int* in_sizes, int n_in,
                              void* d_out, int out_size, void* d_ws, size_t ws_size,
                              hipStream_t stream) {
  const float* h1 = (const float*)d_in[0];
  const float* h2 = (const float*)d_in[1];
  char* ws = (char*)d_ws;

  __hip_bfloat16* Hb = (__hip_bfloat16*)ws;                       // 4 MB
  float* rowsum      = (float*)(ws + 4194304);                    // 64 KB
  float* posdot      = (float*)(ws + 4194304 + 65536);            // 32 KB
  int*   counter     = (int*)(ws + 4194304 + 65536 + 32768);      // 4 B
  float* out         = (float*)d_out;

  norm_kernel<<<N_ROWS / 4, 256, 0, stream>>>(h1, h2, Hb, posdot, rowsum, counter);
  ntx_main<<<NTRI, 512, 0, stream>>>(Hb, rowsum, posdot, counter, out);
}